// Round 7
// baseline (280.339 us; speedup 1.0000x reference)
//
#include <hip/hip_runtime.h>

typedef _Float16 f16;
typedef __attribute__((ext_vector_type(4))) _Float16 f16x4;
typedef __attribute__((ext_vector_type(8))) _Float16 f16x8;
typedef __attribute__((ext_vector_type(4))) float f32x4;

#define BATCH 8
#define NTOK 1025
#define DIM 768
#define HEADS 12
#define HD 64
#define MTOT (BATCH * NTOK)      // 8200
#define MPAD 8320                // 65*128
#define NQP2 1152                // q rows padded to 9*128
#define NKP 1088                 // kv rows padded to 17*64
#define NUMREL 3972

// Explicit DMA drain before barrier: correctness REQUIRES vmcnt(0)
// between global_load_lds issue and s_barrier (prior-session divergence).
#define DMA_FENCE asm volatile("s_waitcnt vmcnt(0)" ::: "memory")

__device__ __forceinline__ int imin(int a, int b) { return a < b ? a : b; }

__device__ __forceinline__ void gl_lds16(const f16* g, f16* l) {
  __builtin_amdgcn_global_load_lds(
      (const __attribute__((address_space(1))) unsigned int*)g,
      (__attribute__((address_space(3))) unsigned int*)l, 16, 0, 0);
}

// ---------------------------------------------------------------------------
// Kernel C: f32 -> f16 cast, 3 arrays in one launch
// ---------------------------------------------------------------------------
__global__ __launch_bounds__(256) void cast3(const float* __restrict__ s0,
                                             f16* __restrict__ d0, int n0,
                                             const float* __restrict__ s1,
                                             f16* __restrict__ d1, int n1,
                                             const float* __restrict__ s2,
                                             f16* __restrict__ d2, int n2) {
  const float* s = (blockIdx.y == 0) ? s0 : (blockIdx.y == 1) ? s1 : s2;
  f16* d = (blockIdx.y == 0) ? d0 : (blockIdx.y == 1) ? d1 : d2;
  int n = (blockIdx.y == 0) ? n0 : (blockIdx.y == 1) ? n1 : n2;
  for (size_t i = ((size_t)blockIdx.x * 256 + threadIdx.x) * 8; i < (size_t)n;
       i += (size_t)gridDim.x * 256 * 8) {
    float4 a = *(const float4*)(s + i);
    float4 b = *(const float4*)(s + i + 4);
    f16x8 r;
    r[0] = (f16)a.x; r[1] = (f16)a.y; r[2] = (f16)a.z; r[3] = (f16)a.w;
    r[4] = (f16)b.x; r[5] = (f16)b.y; r[6] = (f16)b.z; r[7] = (f16)b.w;
    *(f16x8*)(d + i) = r;
  }
}

// ---------------------------------------------------------------------------
// Kernel 0: transpose rpb [NUMREL][HEADS] f32 -> rpbt [HEADS][NUMREL] f32.
// Per-head slab = 15.9 KB: L1-resident inside attn (each block uses one h).
// Replaces the 28.4 MB materialized bias table (2/3 of attn's byte traffic).
// ---------------------------------------------------------------------------
__global__ __launch_bounds__(256) void rpb_t(const float* __restrict__ rpb,
                                             float* __restrict__ rpbt) {
  int i = blockIdx.x * 256 + threadIdx.x;
  if (i >= NUMREL * HEADS) return;
  int idx = i / HEADS, h = i - idx * HEADS;
  rpbt[(size_t)h * NUMREL + idx] = rpb[i];
}

// ---------------------------------------------------------------------------
// Kernel 1: qkv = xh @ wh^T + [q_bias,0,v_bias]; split Q(scaled)/K/V^T.
// BM=128 x BN=256, 512 threads / 8 waves (wave tile 64x64, acc[4][4]),
// BK=64 SINGLE-buffered drain staging. GRID (9,65): tN fast.
// ---------------------------------------------------------------------------
__global__ __launch_bounds__(512) void qkv_gemm(
    const f16* __restrict__ Ah, const f16* __restrict__ Bh,
    const float* __restrict__ q_bias, const float* __restrict__ v_bias,
    f16* __restrict__ qb, f16* __restrict__ kb, f16* __restrict__ vtb) {
  __shared__ f16 As[128][64];  // 16 KB
  __shared__ f16 Bs[256][64];  // 32 KB
  const int tid = threadIdx.x;
  const int lane = tid & 63, w = tid >> 6;   // w: 0..7
  const int wm = w >> 2, wn = w & 3;         // 2 M-halves x 4 N-quarters
  const int lr = lane & 15, lg = lane >> 4;
  const int tN = blockIdx.x;  // 0..8  (fast dim: A-tile sharers adjacent)
  const int tM = blockIdx.y;  // 0..64
  const int r8 = lane >> 3;             // 0..7 (row within 8-row DMA slab)
  const int swch = (lane & 7) ^ r8;     // 8-chunk XOR swizzle (global side)
  const int lr7 = lr & 7;

  const f16* Ab = Ah + ((size_t)tM * 128 + r8) * DIM + swch * 8;
  const f16* Bb = Bh + ((size_t)tN * 256 + r8) * DIM + swch * 8;

  f32x4 acc[4][4] = {};

  for (int kt = 0; kt < 12; kt++) {
    // A: 128 rows over 8 waves -> 2 slabs/wave; B: 256 rows -> 4 slabs/wave.
#pragma unroll
    for (int pp = 0; pp < 2; pp++) {
      int rowb = w * 16 + pp * 8;
      gl_lds16(Ab + (size_t)rowb * DIM + kt * 64, &As[rowb][0]);
    }
#pragma unroll
    for (int pp = 0; pp < 4; pp++) {
      int rowb = w * 32 + pp * 8;
      gl_lds16(Bb + (size_t)rowb * DIM + kt * 64, &Bs[rowb][0]);
    }
    DMA_FENCE;        // own DMA (tile kt) complete before barrier
    __syncthreads();  // all waves' DMA complete -> tile kt readable
#pragma unroll
    for (int ks = 0; ks < 2; ks++) {
      f16x8 af[4], bf[4];
      int rc = ((ks * 4 + lg) ^ lr7) * 8;
#pragma unroll
      for (int i = 0; i < 4; i++) {
        af[i] = *(const f16x8*)(&As[wm * 64 + i * 16 + lr][rc]);
        bf[i] = *(const f16x8*)(&Bs[wn * 64 + i * 16 + lr][rc]);
      }
#pragma unroll
      for (int mi = 0; mi < 4; mi++)
#pragma unroll
        for (int ni = 0; ni < 4; ni++)
          acc[mi][ni] = __builtin_amdgcn_mfma_f32_16x16x32_f16(
              af[mi], bf[ni], acc[mi][ni], 0, 0, 0);
    }
    __syncthreads();  // all reads done before next tile's DMA overwrites
  }

  const int which = tN / 3;   // 0:Q 1:K 2:V (256-col block never crosses)
  const int nb = tN % 3;
#pragma unroll
  for (int mi = 0; mi < 4; mi++) {
#pragma unroll
    for (int ni = 0; ni < 4; ni++) {
      int ncol = nb * 256 + wn * 64 + ni * 16 + lr;  // 0..767
      int h = ncol >> 6, dd = ncol & 63;
      float bias = 0.f;
      if (which == 0) bias = q_bias[ncol];
      if (which == 2) bias = v_bias[ncol];
#pragma unroll
      for (int r = 0; r < 4; r++) {
        int m = tM * 128 + wm * 64 + mi * 16 + lg * 4 + r;
        if (m >= MTOT) continue;
        int b = m / NTOK;
        int t = m - b * NTOK;
        int bh = b * HEADS + h;
        float v = acc[mi][ni][r] + bias;
        if (which == 0)
          qb[((size_t)bh * NQP2 + t) * HD + dd] = (f16)(v * 0.125f);
        else if (which == 1)
          kb[((size_t)bh * NKP + t) * HD + dd] = (f16)v;
        else
          vtb[((size_t)bh * HD + dd) * NKP + t] = (f16)v;
      }
    }
  }
}

// ---------------------------------------------------------------------------
// Kernel 2: fused flash attention. 512 threads / 8 waves; waves 0-3 handle
// qblk 2j, waves 4-7 qblk 2j+1 (K/V staged once per 256 q rows). Bias is
// computed ON THE FLY from the per-head rpbt slab (15.9 KB, L1-resident):
// removes the 15.7 MB/iter grid-wide bias-table stream (2/3 of attn bytes).
// Grid 480 = 8b * 5qpair * 12h; qblk 9 masked by the qg<NTOK store guard.
// ---------------------------------------------------------------------------
__global__ __launch_bounds__(512) void attn_kernel(
    const f16* __restrict__ qb, const f16* __restrict__ kb,
    const f16* __restrict__ vtb, const float* __restrict__ rpbt,
    f16* __restrict__ ob) {
  __shared__ f16 Ks[2][64][64];   // 16 KB
  __shared__ f16 Vs[2][64][64];   // 16 KB
  __shared__ f16 Plds[8][16][72]; // 18 KB
  const int tid = threadIdx.x;
  const int lane = tid & 63, w = tid >> 6;  // w: 0..7
  const int lr = lane & 15, lg = lane >> 4;
  const int b = blockIdx.x & 7;          // fastest
  const int t5 = blockIdx.x >> 3;        // 0..59
  const int qpair = t5 % 5;              // 0..4
  const int h = t5 / 5;                  // 0..11
  const int qblk = qpair * 2 + (w >> 2); // 0..9 (9 = masked pad)
  const int bh = b * HEADS + h;
  const int q0 = qblk * 128 + (w & 3) * 32;

  const f16* kbase = kb + (size_t)bh * NKP * HD;
  const f16* vbase = vtb + (size_t)bh * HD * NKP;

  const int srow8 = lane >> 3;
  const int swch = (lane & 7) ^ srow8;

  // Prologue: 64 K rows + 64 V rows over 8 waves -> 1 slab each per wave.
  {
    int row = w * 8 + srow8;
    gl_lds16(kbase + (size_t)row * HD + swch * 8, &Ks[0][w * 8][0]);
    gl_lds16(vbase + (size_t)row * NKP + swch * 8, &Vs[0][w * 8][0]);
  }

  f16x8 aq[2][2];
#pragma unroll
  for (int g = 0; g < 2; g++) {
    const f16* qp = qb + ((size_t)bh * NQP2 + q0 + g * 16 + lr) * HD + lg * 8;
    aq[g][0] = *(const f16x8*)(qp);
    aq[g][1] = *(const f16x8*)(qp + 32);
  }

  // Per-lane q-row constants for on-the-fly bias:
  // bias(q, kv): q = q0 + g*16 + lr, kv = kt*64 + c*16 + lg*4 + r.
  int qd0[2], qm0[2], qz[2];
#pragma unroll
  for (int g = 0; g < 2; g++) {
    int q = imin(q0 + g * 16 + lr, 1024);  // garbage rows clamp like old tbl
    qz[g] = (q == 0);
    int qq = (q > 0 ? q : 1) - 1;
    qd0[g] = qq >> 5;
    qm0[g] = qq & 31;
  }
  const float* rph = rpbt + (size_t)h * NUMREL;

  float lsum[2] = {0.f, 0.f};
  f32x4 oacc[2][4] = {};
  const int sw8 = lr & 7;

  for (int kt = 0; kt < 17; kt++) {
    const int bi = kt & 1;
    DMA_FENCE;        // own DMA (tile kt) complete before barrier
    __syncthreads();
    if (kt + 1 < 17) {
      int row = w * 8 + srow8;
      gl_lds16(kbase + (size_t)((kt + 1) * 64 + row) * HD + swch * 8,
               &Ks[bi ^ 1][w * 8][0]);
      gl_lds16(vbase + (size_t)row * NKP + (kt + 1) * 64 + swch * 8,
               &Vs[bi ^ 1][w * 8][0]);
    }
    // S init = bias, computed on the fly (gathers hit the L1-resident rph).
    f32x4 s[2][4];
#pragma unroll
    for (int c = 0; c < 4; c++)
#pragma unroll
      for (int r = 0; r < 4; r++) {
        int kv = kt * 64 + c * 16 + lg * 4 + r;
        int kk = kv - 1;
        int kd = kk >> 5, km = kk & 31;  // kv==0 -> overridden below
#pragma unroll
        for (int g = 0; g < 2; g++) {
          int idx = (qd0[g] - kd + 31) * 63 + (qm0[g] - km + 31);
          idx = qz[g] ? (NUMREL - 3) : idx;
          if (kv == 0) idx = qz[g] ? (NUMREL - 1) : (NUMREL - 2);
          idx = (kv >= NTOK) ? 0 : idx;   // clamp (value replaced below)
          float bv = rph[idx];
          s[g][c][r] = (kv >= NTOK) ? -30000.f : bv;
        }
      }
#pragma unroll
    for (int c = 0; c < 4; c++) {
      f16x8 kf0 = *(const f16x8*)(&Ks[bi][c * 16 + lr][(lg ^ sw8) * 8]);
      f16x8 kf1 = *(const f16x8*)(&Ks[bi][c * 16 + lr][((lg + 4) ^ sw8) * 8]);
      s[0][c] = __builtin_amdgcn_mfma_f32_16x16x32_f16(kf0, aq[0][0], s[0][c], 0, 0, 0);
      s[0][c] = __builtin_amdgcn_mfma_f32_16x16x32_f16(kf1, aq[0][1], s[0][c], 0, 0, 0);
      s[1][c] = __builtin_amdgcn_mfma_f32_16x16x32_f16(kf0, aq[1][0], s[1][c], 0, 0, 0);
      s[1][c] = __builtin_amdgcn_mfma_f32_16x16x32_f16(kf1, aq[1][1], s[1][c], 0, 0, 0);
    }
#pragma unroll
    for (int g = 0; g < 2; g++)
#pragma unroll
      for (int c = 0; c < 4; c++)
#pragma unroll
        for (int r = 0; r < 4; r++) {
          float p = __expf(s[g][c][r]);
          s[g][c][r] = p;
          lsum[g] += p;
        }
    f16x8 ap[2][2];
#pragma unroll
    for (int g = 0; g < 2; g++) {
#pragma unroll
      for (int c = 0; c < 4; c++) {
        f16x4 pk;
        pk[0] = (f16)s[g][c][0];
        pk[1] = (f16)s[g][c][1];
        pk[2] = (f16)s[g][c][2];
        pk[3] = (f16)s[g][c][3];
        *(f16x4*)(&Plds[w][lr][c * 16 + lg * 4]) = pk;
      }
      ap[g][0] = *(const f16x8*)(&Plds[w][lr][lg * 8]);
      ap[g][1] = *(const f16x8*)(&Plds[w][lr][32 + lg * 8]);
    }
#pragma unroll
    for (int dblk = 0; dblk < 4; dblk++) {
      f16x8 vf0 = *(const f16x8*)(&Vs[bi][dblk * 16 + lr][(lg ^ sw8) * 8]);
      f16x8 vf1 = *(const f16x8*)(&Vs[bi][dblk * 16 + lr][((lg + 4) ^ sw8) * 8]);
      oacc[0][dblk] = __builtin_amdgcn_mfma_f32_16x16x32_f16(ap[0][0], vf0, oacc[0][dblk], 0, 0, 0);
      oacc[0][dblk] = __builtin_amdgcn_mfma_f32_16x16x32_f16(ap[0][1], vf1, oacc[0][dblk], 0, 0, 0);
      oacc[1][dblk] = __builtin_amdgcn_mfma_f32_16x16x32_f16(ap[1][0], vf0, oacc[1][dblk], 0, 0, 0);
      oacc[1][dblk] = __builtin_amdgcn_mfma_f32_16x16x32_f16(ap[1][1], vf1, oacc[1][dblk], 0, 0, 0);
    }
  }
#pragma unroll
  for (int g = 0; g < 2; g++) {
    float ls = lsum[g];
    ls += __shfl_xor(ls, 16);
    ls += __shfl_xor(ls, 32);
    float inv[4];
#pragma unroll
    for (int r = 0; r < 4; r++) inv[r] = 1.f / __shfl(ls, lg * 4 + r);
#pragma unroll
    for (int dblk = 0; dblk < 4; dblk++)
#pragma unroll
      for (int r = 0; r < 4; r++) {
        int qg = q0 + g * 16 + lg * 4 + r;
        if (qg >= NTOK) continue;
        float v = oacc[g][dblk][r] * inv[r];
        ob[((size_t)(b * NTOK + qg)) * DIM + h * HD + dblk * 16 + lr] = (f16)v;
      }
  }
}

// ---------------------------------------------------------------------------
// Kernel 3: out = ob @ pwh^T + proj_b. BM=128 x BN=256, 512 threads / 8
// waves (wave 64x64), BK=64 single-buffered. GRID (3,65): tN fast.
// ---------------------------------------------------------------------------
__global__ __launch_bounds__(512) void proj_gemm(const f16* __restrict__ Ah,
                                                 const f16* __restrict__ Bh,
                                                 const float* __restrict__ pb,
                                                 float* __restrict__ out) {
  __shared__ f16 As[128][64];
  __shared__ f16 Bs[256][64];
  const int tid = threadIdx.x;
  const int lane = tid & 63, w = tid >> 6;
  const int wm = w >> 2, wn = w & 3;
  const int lr = lane & 15, lg = lane >> 4;
  const int tN = blockIdx.x;  // 0..2  (fast dim)
  const int tM = blockIdx.y;  // 0..64
  const int r8 = lane >> 3;
  const int swch = (lane & 7) ^ r8;
  const int lr7 = lr & 7;

  const f16* Ab = Ah + ((size_t)tM * 128 + r8) * DIM + swch * 8;
  const f16* Bb = Bh + ((size_t)tN * 256 + r8) * DIM + swch * 8;

  f32x4 acc[4][4] = {};

  for (int kt = 0; kt < 12; kt++) {
#pragma unroll
    for (int pp = 0; pp < 2; pp++) {
      int rowb = w * 16 + pp * 8;
      gl_lds16(Ab + (size_t)rowb * DIM + kt * 64, &As[rowb][0]);
    }
#pragma unroll
    for (int pp = 0; pp < 4; pp++) {
      int rowb = w * 32 + pp * 8;
      gl_lds16(Bb + (size_t)rowb * DIM + kt * 64, &Bs[rowb][0]);
    }
    DMA_FENCE;
    __syncthreads();
#pragma unroll
    for (int ks = 0; ks < 2; ks++) {
      f16x8 af[4], bf[4];
      int rc = ((ks * 4 + lg) ^ lr7) * 8;
#pragma unroll
      for (int i = 0; i < 4; i++) {
        af[i] = *(const f16x8*)(&As[wm * 64 + i * 16 + lr][rc]);
        bf[i] = *(const f16x8*)(&Bs[wn * 64 + i * 16 + lr][rc]);
      }
#pragma unroll
      for (int mi = 0; mi < 4; mi++)
#pragma unroll
        for (int ni = 0; ni < 4; ni++)
          acc[mi][ni] = __builtin_amdgcn_mfma_f32_16x16x32_f16(
              af[mi], bf[ni], acc[mi][ni], 0, 0, 0);
    }
    __syncthreads();
  }

#pragma unroll
  for (int mi = 0; mi < 4; mi++) {
#pragma unroll
    for (int ni = 0; ni < 4; ni++) {
      int n = tN * 256 + wn * 64 + ni * 16 + lr;
      float bias = pb[n];
#pragma unroll
      for (int r = 0; r < 4; r++) {
        int m = tM * 128 + wm * 64 + mi * 16 + lg * 4 + r;
        if (m >= MTOT) continue;
        out[(size_t)m * DIM + n] = acc[mi][ni][r] + bias;
      }
    }
  }
}

extern "C" void kernel_launch(void* const* d_in, const int* in_sizes, int n_in,
                              void* d_out, int out_size, void* d_ws,
                              size_t ws_size, hipStream_t stream) {
  const float* x = (const float*)d_in[0];
  const float* qkv_w = (const float*)d_in[1];
  const float* q_bias = (const float*)d_in[2];
  const float* v_bias = (const float*)d_in[3];
  const float* rpb = (const float*)d_in[4];
  const float* proj_w = (const float*)d_in[5];
  const float* proj_b = (const float*)d_in[6];
  float* out = (float*)d_out;

  f16* xh = (f16*)d_ws;                        // [MPAD,768]
  f16* wh = xh + (size_t)MPAD * DIM;           // [2304,768]
  f16* pwh = wh + (size_t)3 * DIM * DIM;       // [768,768]
  f16* qb = pwh + (size_t)DIM * DIM;           // [96,1152,64]
  f16* kb = qb + (size_t)BATCH * HEADS * NQP2 * HD;
  f16* vtb = kb + (size_t)BATCH * HEADS * NKP * HD;
  f16* ob = vtb + (size_t)BATCH * HEADS * NKP * HD;  // [MPAD,768]
  float* rpbt = (float*)(ob + (size_t)MPAD * DIM);   // [12][3972] f32

  cast3<<<dim3(1024, 3), 256, 0, stream>>>(
      x, xh, MTOT * DIM, qkv_w, wh, 3 * DIM * DIM, proj_w, pwh, DIM * DIM);
  rpb_t<<<dim3(187), 256, 0, stream>>>(rpb, rpbt);
  qkv_gemm<<<dim3(9, 65), 512, 0, stream>>>(xh, wh, q_bias, v_bias, qb, kb,
                                            vtb);
  attn_kernel<<<dim3(BATCH * 5 * HEADS), 512, 0, stream>>>(qb, kb, vtb, rpbt,
                                                           ob);
  proj_gemm<<<dim3(3, 65), 512, 0, stream>>>(ob, pwh, proj_b, out);
}

// Round 8
// 278.103 us; speedup vs baseline: 1.0080x; 1.0080x over previous
//
#include <hip/hip_runtime.h>

typedef _Float16 f16;
typedef __attribute__((ext_vector_type(4))) _Float16 f16x4;
typedef __attribute__((ext_vector_type(8))) _Float16 f16x8;
typedef __attribute__((ext_vector_type(4))) float f32x4;

#define BATCH 8
#define NTOK 1025
#define DIM 768
#define HEADS 12
#define HD 64
#define MTOT (BATCH * NTOK)      // 8200
#define MPAD 8320                // 65*128
#define NQP2 1152                // q rows padded to 9*128
#define NKP 1088                 // kv rows padded to 17*64
#define NUMREL 3972

// Explicit DMA drain before barrier (GEMM kernels): correctness REQUIRES
// vmcnt(0) between global_load_lds issue and s_barrier.
#define DMA_FENCE asm volatile("s_waitcnt vmcnt(0)" ::: "memory")

__device__ __forceinline__ int imin(int a, int b) { return a < b ? a : b; }

__device__ __forceinline__ void gl_lds16(const f16* g, f16* l) {
  __builtin_amdgcn_global_load_lds(
      (const __attribute__((address_space(1))) unsigned int*)g,
      (__attribute__((address_space(3))) unsigned int*)l, 16, 0, 0);
}

// ---------------------------------------------------------------------------
// Kernel C: f32 -> f16 cast, 3 arrays in one launch
// ---------------------------------------------------------------------------
__global__ __launch_bounds__(256) void cast3(const float* __restrict__ s0,
                                             f16* __restrict__ d0, int n0,
                                             const float* __restrict__ s1,
                                             f16* __restrict__ d1, int n1,
                                             const float* __restrict__ s2,
                                             f16* __restrict__ d2, int n2) {
  const float* s = (blockIdx.y == 0) ? s0 : (blockIdx.y == 1) ? s1 : s2;
  f16* d = (blockIdx.y == 0) ? d0 : (blockIdx.y == 1) ? d1 : d2;
  int n = (blockIdx.y == 0) ? n0 : (blockIdx.y == 1) ? n1 : n2;
  for (size_t i = ((size_t)blockIdx.x * 256 + threadIdx.x) * 8; i < (size_t)n;
       i += (size_t)gridDim.x * 256 * 8) {
    float4 a = *(const float4*)(s + i);
    float4 b = *(const float4*)(s + i + 4);
    f16x8 r;
    r[0] = (f16)a.x; r[1] = (f16)a.y; r[2] = (f16)a.z; r[3] = (f16)a.w;
    r[4] = (f16)b.x; r[5] = (f16)b.y; r[6] = (f16)b.z; r[7] = (f16)b.w;
    *(f16x8*)(d + i) = r;
  }
}

// ---------------------------------------------------------------------------
// Kernel 0: transpose rpb [NUMREL][HEADS] f32 -> rpbt [HEADS][NUMREL] f32.
// Per-head slab = 15.9 KB: L1-resident inside attn (each block uses one h).
// ---------------------------------------------------------------------------
__global__ __launch_bounds__(256) void rpb_t(const float* __restrict__ rpb,
                                             float* __restrict__ rpbt) {
  int i = blockIdx.x * 256 + threadIdx.x;
  if (i >= NUMREL * HEADS) return;
  int idx = i / HEADS, h = i - idx * HEADS;
  rpbt[(size_t)h * NUMREL + idx] = rpb[i];
}

// ---------------------------------------------------------------------------
// Kernel 1: qkv = xh @ wh^T + [q_bias,0,v_bias]; split Q(scaled)/K/V^T.
// BM=128 x BN=256, 512 threads / 8 waves (wave tile 64x64, acc[4][4]),
// BK=64 SINGLE-buffered drain staging. GRID (9,65): tN fast.
// ---------------------------------------------------------------------------
__global__ __launch_bounds__(512) void qkv_gemm(
    const f16* __restrict__ Ah, const f16* __restrict__ Bh,
    const float* __restrict__ q_bias, const float* __restrict__ v_bias,
    f16* __restrict__ qb, f16* __restrict__ kb, f16* __restrict__ vtb) {
  __shared__ f16 As[128][64];  // 16 KB
  __shared__ f16 Bs[256][64];  // 32 KB
  const int tid = threadIdx.x;
  const int lane = tid & 63, w = tid >> 6;   // w: 0..7
  const int wm = w >> 2, wn = w & 3;         // 2 M-halves x 4 N-quarters
  const int lr = lane & 15, lg = lane >> 4;
  const int tN = blockIdx.x;  // 0..8  (fast dim: A-tile sharers adjacent)
  const int tM = blockIdx.y;  // 0..64
  const int r8 = lane >> 3;             // 0..7 (row within 8-row DMA slab)
  const int swch = (lane & 7) ^ r8;     // 8-chunk XOR swizzle (global side)
  const int lr7 = lr & 7;

  const f16* Ab = Ah + ((size_t)tM * 128 + r8) * DIM + swch * 8;
  const f16* Bb = Bh + ((size_t)tN * 256 + r8) * DIM + swch * 8;

  f32x4 acc[4][4] = {};

  for (int kt = 0; kt < 12; kt++) {
    // A: 128 rows over 8 waves -> 2 slabs/wave; B: 256 rows -> 4 slabs/wave.
#pragma unroll
    for (int pp = 0; pp < 2; pp++) {
      int rowb = w * 16 + pp * 8;
      gl_lds16(Ab + (size_t)rowb * DIM + kt * 64, &As[rowb][0]);
    }
#pragma unroll
    for (int pp = 0; pp < 4; pp++) {
      int rowb = w * 32 + pp * 8;
      gl_lds16(Bb + (size_t)rowb * DIM + kt * 64, &Bs[rowb][0]);
    }
    DMA_FENCE;        // own DMA (tile kt) complete before barrier
    __syncthreads();  // all waves' DMA complete -> tile kt readable
#pragma unroll
    for (int ks = 0; ks < 2; ks++) {
      f16x8 af[4], bf[4];
      int rc = ((ks * 4 + lg) ^ lr7) * 8;
#pragma unroll
      for (int i = 0; i < 4; i++) {
        af[i] = *(const f16x8*)(&As[wm * 64 + i * 16 + lr][rc]);
        bf[i] = *(const f16x8*)(&Bs[wn * 64 + i * 16 + lr][rc]);
      }
#pragma unroll
      for (int mi = 0; mi < 4; mi++)
#pragma unroll
        for (int ni = 0; ni < 4; ni++)
          acc[mi][ni] = __builtin_amdgcn_mfma_f32_16x16x32_f16(
              af[mi], bf[ni], acc[mi][ni], 0, 0, 0);
    }
    __syncthreads();  // all reads done before next tile's DMA overwrites
  }

  const int which = tN / 3;   // 0:Q 1:K 2:V (256-col block never crosses)
  const int nb = tN % 3;
#pragma unroll
  for (int mi = 0; mi < 4; mi++) {
#pragma unroll
    for (int ni = 0; ni < 4; ni++) {
      int ncol = nb * 256 + wn * 64 + ni * 16 + lr;  // 0..767
      int h = ncol >> 6, dd = ncol & 63;
      float bias = 0.f;
      if (which == 0) bias = q_bias[ncol];
      if (which == 2) bias = v_bias[ncol];
#pragma unroll
      for (int r = 0; r < 4; r++) {
        int m = tM * 128 + wm * 64 + mi * 16 + lg * 4 + r;
        if (m >= MTOT) continue;
        int b = m / NTOK;
        int t = m - b * NTOK;
        int bh = b * HEADS + h;
        float v = acc[mi][ni][r] + bias;
        if (which == 0)
          qb[((size_t)bh * NQP2 + t) * HD + dd] = (f16)(v * 0.125f);
        else if (which == 1)
          kb[((size_t)bh * NKP + t) * HD + dd] = (f16)v;
        else
          vtb[((size_t)bh * HD + dd) * NKP + t] = (f16)v;
      }
    }
  }
}

// ---------------------------------------------------------------------------
// Kernel 2: fused flash attention, T14 async-stage split.
// K/V tile kt+1 is loaded into REGISTERS (plain global loads, 16 B/lane)
// during iter kt's compute, then written to SINGLE-buffered LDS between two
// __syncthreads (textbook scheme; barriers drain vmcnt/lgkmcnt -> race-safe).
// Bias computed on the fly from the L1-resident per-head rpbt slab, but
// prefetched ONE ITERATION AHEAD into f16 regs (R6's bb/nb pipeline) so the
// gathers never sit on the QK^T critical path (R7's mistake).
// LDS 34 KB. Grid 480 = 8b * 5qpair * 12h; qblk 9 masked by qg<NTOK guard.
// ---------------------------------------------------------------------------
__global__ __launch_bounds__(512) void attn_kernel(
    const f16* __restrict__ qb, const f16* __restrict__ kb,
    const f16* __restrict__ vtb, const float* __restrict__ rpbt,
    f16* __restrict__ ob) {
  __shared__ f16 Ks[64][64];      // 8 KB (single buffer)
  __shared__ f16 Vs[64][64];      // 8 KB
  __shared__ f16 Plds[8][16][72]; // 18 KB
  const int tid = threadIdx.x;
  const int lane = tid & 63, w = tid >> 6;  // w: 0..7
  const int lr = lane & 15, lg = lane >> 4;
  const int b = blockIdx.x & 7;          // fastest
  const int t5 = blockIdx.x >> 3;        // 0..59
  const int qpair = t5 % 5;              // 0..4
  const int h = t5 / 5;                  // 0..11
  const int qblk = qpair * 2 + (w >> 2); // 0..9 (9 = masked pad)
  const int bh = b * HEADS + h;
  const int q0 = qblk * 128 + (w & 3) * 32;

  const f16* kbase = kb + (size_t)bh * NKP * HD;
  const f16* vbase = vtb + (size_t)bh * HD * NKP;

  const int srow8 = lane >> 3;
  const int swch = (lane & 7) ^ srow8;   // matches gl_lds16 layout exactly:
  const int row = w * 8 + srow8;         // lane i -> LDS row w*8+(i>>3), chunk i&7

  // --- T14: registers hold tile kt+1 while LDS holds tile kt ---
  f16x8 rk = *(const f16x8*)(kbase + (size_t)row * HD + swch * 8);
  f16x8 rv = *(const f16x8*)(vbase + (size_t)row * NKP + swch * 8);

  f16x8 aq[2][2];
#pragma unroll
  for (int g = 0; g < 2; g++) {
    const f16* qp = qb + ((size_t)bh * NQP2 + q0 + g * 16 + lr) * HD + lg * 8;
    aq[g][0] = *(const f16x8*)(qp);
    aq[g][1] = *(const f16x8*)(qp + 32);
  }

  // Per-lane q-row constants for on-the-fly bias.
  int qz[2], qbase[2];
#pragma unroll
  for (int g = 0; g < 2; g++) {
    int q = imin(q0 + g * 16 + lr, 1024);  // garbage rows clamp (masked later)
    qz[g] = (q == 0);
    int qq = (q > 0 ? q : 1) - 1;
    qbase[g] = ((qq >> 5) + 31) * 63 + (qq & 31) + 31;
  }
  const float* rph = rpbt + (size_t)h * NUMREL;

// Gather bias for tile KT into f16x8 DST[2][2] (layout == old tbl fragment:
// DST[g][c>>1] holds vals[(c&1)*4+r]). Issued mid-iter, consumed next iter.
#define FETCH_BIAS(KT, DST)                                                   \
  {                                                                           \
    _Pragma("unroll") for (int g = 0; g < 2; g++) {                           \
      f16 vals[16];                                                           \
      _Pragma("unroll") for (int c = 0; c < 4; c++)                           \
          _Pragma("unroll") for (int r = 0; r < 4; r++) {                     \
        int kv = (KT) * 64 + c * 16 + lg * 4 + r;                             \
        int kk = kv - 1;                                                      \
        int t = (kk >> 5) * 63 + (kk & 31);                                   \
        int idx = qbase[g] - t;                                               \
        idx = qz[g] ? (NUMREL - 3) : idx;                                     \
        if (kv == 0) idx = qz[g] ? (NUMREL - 1) : (NUMREL - 2);               \
        idx = (kv >= NTOK) ? 0 : idx;                                         \
        float bv = rph[idx];                                                  \
        vals[c * 4 + r] = (f16)((kv >= NTOK) ? -30000.f : bv);                \
      }                                                                       \
      DST[g][0] = *(const f16x8*)(&vals[0]);                                  \
      DST[g][1] = *(const f16x8*)(&vals[8]);                                  \
    }                                                                         \
  }

  f16x8 bb[2][2], nb[2][2];
  FETCH_BIAS(0, bb);

  // Stage tile 0 (compiler inserts vmcnt wait on rk/rv before the ds_write).
  *(f16x8*)(&Ks[w * 8][0] + lane * 8) = rk;
  *(f16x8*)(&Vs[w * 8][0] + lane * 8) = rv;
  __syncthreads();  // tile 0 visible
  // Issue loads for tile 1.
  rk = *(const f16x8*)(kbase + (size_t)(64 + row) * HD + swch * 8);
  rv = *(const f16x8*)(vbase + (size_t)row * NKP + 64 + swch * 8);

  float lsum[2] = {0.f, 0.f};
  f32x4 oacc[2][4] = {};
  const int sw8 = lr & 7;

  for (int kt = 0; kt < 17; kt++) {
    // S init = bias (from regs prefetched last iter — off the critical path).
    f32x4 s[2][4];
#pragma unroll
    for (int g = 0; g < 2; g++)
#pragma unroll
      for (int c = 0; c < 4; c++) {
        const f16* src = (const f16*)&bb[g][c >> 1];
#pragma unroll
        for (int r = 0; r < 4; r++) s[g][c][r] = (float)src[(c & 1) * 4 + r];
      }
#pragma unroll
    for (int c = 0; c < 4; c++) {
      f16x8 kf0 = *(const f16x8*)(&Ks[c * 16 + lr][(lg ^ sw8) * 8]);
      f16x8 kf1 = *(const f16x8*)(&Ks[c * 16 + lr][((lg + 4) ^ sw8) * 8]);
      s[0][c] = __builtin_amdgcn_mfma_f32_16x16x32_f16(kf0, aq[0][0], s[0][c], 0, 0, 0);
      s[0][c] = __builtin_amdgcn_mfma_f32_16x16x32_f16(kf1, aq[0][1], s[0][c], 0, 0, 0);
      s[1][c] = __builtin_amdgcn_mfma_f32_16x16x32_f16(kf0, aq[1][0], s[1][c], 0, 0, 0);
      s[1][c] = __builtin_amdgcn_mfma_f32_16x16x32_f16(kf1, aq[1][1], s[1][c], 0, 0, 0);
    }
    // Prefetch bias for next tile (L1 gathers, hidden under exp+PV below).
    if (kt + 1 < 17) FETCH_BIAS(kt + 1, nb);
#pragma unroll
    for (int g = 0; g < 2; g++)
#pragma unroll
      for (int c = 0; c < 4; c++)
#pragma unroll
        for (int r = 0; r < 4; r++) {
          float p = __expf(s[g][c][r]);
          s[g][c][r] = p;
          lsum[g] += p;
        }
    f16x8 ap[2][2];
#pragma unroll
    for (int g = 0; g < 2; g++) {
#pragma unroll
      for (int c = 0; c < 4; c++) {
        f16x4 pk;
        pk[0] = (f16)s[g][c][0];
        pk[1] = (f16)s[g][c][1];
        pk[2] = (f16)s[g][c][2];
        pk[3] = (f16)s[g][c][3];
        *(f16x4*)(&Plds[w][lr][c * 16 + lg * 4]) = pk;
      }
      ap[g][0] = *(const f16x8*)(&Plds[w][lr][lg * 8]);
      ap[g][1] = *(const f16x8*)(&Plds[w][lr][32 + lg * 8]);
    }
#pragma unroll
    for (int dblk = 0; dblk < 4; dblk++) {
      f16x8 vf0 = *(const f16x8*)(&Vs[dblk * 16 + lr][(lg ^ sw8) * 8]);
      f16x8 vf1 = *(const f16x8*)(&Vs[dblk * 16 + lr][((lg + 4) ^ sw8) * 8]);
      oacc[0][dblk] = __builtin_amdgcn_mfma_f32_16x16x32_f16(ap[0][0], vf0, oacc[0][dblk], 0, 0, 0);
      oacc[0][dblk] = __builtin_amdgcn_mfma_f32_16x16x32_f16(ap[0][1], vf1, oacc[0][dblk], 0, 0, 0);
      oacc[1][dblk] = __builtin_amdgcn_mfma_f32_16x16x32_f16(ap[1][0], vf0, oacc[1][dblk], 0, 0, 0);
      oacc[1][dblk] = __builtin_amdgcn_mfma_f32_16x16x32_f16(ap[1][1], vf1, oacc[1][dblk], 0, 0, 0);
    }
    if (kt + 1 < 17) {
      __syncthreads();  // B1: all waves done reading tile kt (drains vmcnt too)
      *(f16x8*)(&Ks[w * 8][0] + lane * 8) = rk;   // write tile kt+1
      *(f16x8*)(&Vs[w * 8][0] + lane * 8) = rv;
      __syncthreads();  // B2: tile kt+1 visible
      if (kt + 2 < 17) {  // issue loads for kt+2 (hidden under next compute)
        rk = *(const f16x8*)(kbase + (size_t)((kt + 2) * 64 + row) * HD + swch * 8);
        rv = *(const f16x8*)(vbase + (size_t)row * NKP + (kt + 2) * 64 + swch * 8);
      }
    }
#pragma unroll
    for (int g = 0; g < 2; g++) {
      bb[g][0] = nb[g][0];
      bb[g][1] = nb[g][1];
    }
  }
#pragma unroll
  for (int g = 0; g < 2; g++) {
    float ls = lsum[g];
    ls += __shfl_xor(ls, 16);
    ls += __shfl_xor(ls, 32);
    float inv[4];
#pragma unroll
    for (int r = 0; r < 4; r++) inv[r] = 1.f / __shfl(ls, lg * 4 + r);
#pragma unroll
    for (int dblk = 0; dblk < 4; dblk++)
#pragma unroll
      for (int r = 0; r < 4; r++) {
        int qg = q0 + g * 16 + lg * 4 + r;
        if (qg >= NTOK) continue;
        float v = oacc[g][dblk][r] * inv[r];
        ob[((size_t)(b * NTOK + qg)) * DIM + h * HD + dblk * 16 + lr] = (f16)v;
      }
  }
}

// ---------------------------------------------------------------------------
// Kernel 3: out = ob @ pwh^T + proj_b. BM=128 x BN=256, 512 threads / 8
// waves (wave 64x64), BK=64 single-buffered. GRID (3,65): tN fast.
// ---------------------------------------------------------------------------
__global__ __launch_bounds__(512) void proj_gemm(const f16* __restrict__ Ah,
                                                 const f16* __restrict__ Bh,
                                                 const float* __restrict__ pb,
                                                 float* __restrict__ out) {
  __shared__ f16 As[128][64];
  __shared__ f16 Bs[256][64];
  const int tid = threadIdx.x;
  const int lane = tid & 63, w = tid >> 6;
  const int wm = w >> 2, wn = w & 3;
  const int lr = lane & 15, lg = lane >> 4;
  const int tN = blockIdx.x;  // 0..2  (fast dim)
  const int tM = blockIdx.y;  // 0..64
  const int r8 = lane >> 3;
  const int swch = (lane & 7) ^ r8;
  const int lr7 = lr & 7;

  const f16* Ab = Ah + ((size_t)tM * 128 + r8) * DIM + swch * 8;
  const f16* Bb = Bh + ((size_t)tN * 256 + r8) * DIM + swch * 8;

  f32x4 acc[4][4] = {};

  for (int kt = 0; kt < 12; kt++) {
#pragma unroll
    for (int pp = 0; pp < 2; pp++) {
      int rowb = w * 16 + pp * 8;
      gl_lds16(Ab + (size_t)rowb * DIM + kt * 64, &As[rowb][0]);
    }
#pragma unroll
    for (int pp = 0; pp < 4; pp++) {
      int rowb = w * 32 + pp * 8;
      gl_lds16(Bb + (size_t)rowb * DIM + kt * 64, &Bs[rowb][0]);
    }
    DMA_FENCE;
    __syncthreads();
#pragma unroll
    for (int ks = 0; ks < 2; ks++) {
      f16x8 af[4], bf[4];
      int rc = ((ks * 4 + lg) ^ lr7) * 8;
#pragma unroll
      for (int i = 0; i < 4; i++) {
        af[i] = *(const f16x8*)(&As[wm * 64 + i * 16 + lr][rc]);
        bf[i] = *(const f16x8*)(&Bs[wn * 64 + i * 16 + lr][rc]);
      }
#pragma unroll
      for (int mi = 0; mi < 4; mi++)
#pragma unroll
        for (int ni = 0; ni < 4; ni++)
          acc[mi][ni] = __builtin_amdgcn_mfma_f32_16x16x32_f16(
              af[mi], bf[ni], acc[mi][ni], 0, 0, 0);
    }
    __syncthreads();
  }

#pragma unroll
  for (int mi = 0; mi < 4; mi++) {
#pragma unroll
    for (int ni = 0; ni < 4; ni++) {
      int n = tN * 256 + wn * 64 + ni * 16 + lr;
      float bias = pb[n];
#pragma unroll
      for (int r = 0; r < 4; r++) {
        int m = tM * 128 + wm * 64 + mi * 16 + lg * 4 + r;
        if (m >= MTOT) continue;
        out[(size_t)m * DIM + n] = acc[mi][ni][r] + bias;
      }
    }
  }
}

extern "C" void kernel_launch(void* const* d_in, const int* in_sizes, int n_in,
                              void* d_out, int out_size, void* d_ws,
                              size_t ws_size, hipStream_t stream) {
  const float* x = (const float*)d_in[0];
  const float* qkv_w = (const float*)d_in[1];
  const float* q_bias = (const float*)d_in[2];
  const float* v_bias = (const float*)d_in[3];
  const float* rpb = (const float*)d_in[4];
  const float* proj_w = (const float*)d_in[5];
  const float* proj_b = (const float*)d_in[6];
  float* out = (float*)d_out;

  f16* xh = (f16*)d_ws;                        // [MPAD,768]
  f16* wh = xh + (size_t)MPAD * DIM;           // [2304,768]
  f16* pwh = wh + (size_t)3 * DIM * DIM;       // [768,768]
  f16* qb = pwh + (size_t)DIM * DIM;           // [96,1152,64]
  f16* kb = qb + (size_t)BATCH * HEADS * NQP2 * HD;
  f16* vtb = kb + (size_t)BATCH * HEADS * NKP * HD;
  f16* ob = vtb + (size_t)BATCH * HEADS * NKP * HD;  // [MPAD,768]
  float* rpbt = (float*)(ob + (size_t)MPAD * DIM);   // [12][3972] f32

  cast3<<<dim3(1024, 3), 256, 0, stream>>>(
      x, xh, MTOT * DIM, qkv_w, wh, 3 * DIM * DIM, proj_w, pwh, DIM * DIM);
  rpb_t<<<dim3(187), 256, 0, stream>>>(rpb, rpbt);
  qkv_gemm<<<dim3(9, 65), 512, 0, stream>>>(xh, wh, q_bias, v_bias, qb, kb,
                                            vtb);
  attn_kernel<<<dim3(BATCH * 5 * HEADS), 512, 0, stream>>>(qb, kb, vtb, rpbt,
                                                           ob);
  proj_gemm<<<dim3(3, 65), 512, 0, stream>>>(ob, pwh, proj_b, out);
}